// Round 1
// baseline (703.358 us; speedup 1.0000x reference)
//
#include <hip/hip_runtime.h>
#include <hip/hip_bf16.h>

#define B_ 8
#define N_ 512
#define D_ 512
#define H_ 8
#define DK_ 64

// 1000^(-f/8), f=0..7 (double-evaluated, f32-rounded)
__device__ const float DM_[8] = {
    1.0f, 0.42169650342905464f, 0.1778279410038923f, 0.07498942093324559f,
    0.03162277660168379f, 0.013335214321633241f, 0.005623413251903491f,
    0.0023713737056616554f};

__device__ inline float bf2f(unsigned short u) {
    unsigned int x = ((unsigned int)u) << 16;
    return __uint_as_float(x);
}
__device__ inline unsigned short f2bf(float f) {
    unsigned int x = __float_as_uint(f);
    unsigned int r = (x + 0x7fffu + ((x >> 16) & 1u)) >> 16;  // RNE
    return (unsigned short)r;
}

// ---------------------------------------------------------------------------
// K1: fused Q/K/V projection. C(4096x512) = X(4096x512) @ W^T + b, written as
// (B,H,N,DK). blockIdx.z selects q/k/v. 64x64 tile, 4x4 per thread, fp32.
// ---------------------------------------------------------------------------
__global__ __launch_bounds__(256) void k_proj(
    const float* __restrict__ Xq, const float* __restrict__ Xk, const float* __restrict__ Xv,
    const float* __restrict__ Wq, const float* __restrict__ Wk, const float* __restrict__ Wv,
    const float* __restrict__ bq, const float* __restrict__ bk, const float* __restrict__ bv,
    float* __restrict__ oq, float* __restrict__ ok, float* __restrict__ ov)
{
    const int z = blockIdx.z;
    const float* X = (z == 0) ? Xq : (z == 1) ? Xk : Xv;
    const float* W = (z == 0) ? Wq : (z == 1) ? Wk : Wv;
    const float* bias = (z == 0) ? bq : (z == 1) ? bk : bv;
    float* out = (z == 0) ? oq : (z == 1) ? ok : ov;

    const int m0 = blockIdx.x * 64;   // rows (B*N flat)
    const int n0 = blockIdx.y * 64;   // cols (D)

    __shared__ float As[16][68];
    __shared__ float Bs[16][68];

    const int t = threadIdx.x;
    const int tm = (t & 15) * 4;
    const int tn = (t >> 4) * 4;
    const int lk = t & 15;
    const int lm4 = (t >> 4) * 4;

    float acc[4][4] = {};

    for (int k0 = 0; k0 < 512; k0 += 16) {
#pragma unroll
        for (int i = 0; i < 4; ++i)
            As[lk][lm4 + i] = X[(size_t)(m0 + lm4 + i) * 512 + k0 + lk];
#pragma unroll
        for (int i = 0; i < 4; ++i)
            Bs[lk][lm4 + i] = W[(size_t)(n0 + lm4 + i) * 512 + k0 + lk];
        __syncthreads();
#pragma unroll
        for (int kk = 0; kk < 16; ++kk) {
            float4 a = *(const float4*)&As[kk][tm];
            float4 b = *(const float4*)&Bs[kk][tn];
            const float av[4] = {a.x, a.y, a.z, a.w};
            const float bv4[4] = {b.x, b.y, b.z, b.w};
#pragma unroll
            for (int i = 0; i < 4; ++i)
#pragma unroll
                for (int j = 0; j < 4; ++j) acc[i][j] += av[i] * bv4[j];
        }
        __syncthreads();
    }

#pragma unroll
    for (int i = 0; i < 4; ++i) {
        const int r = m0 + tm + i;
        const int bb = r >> 9, nn = r & 511;
#pragma unroll
        for (int j = 0; j < 4; ++j) {
            const int c = n0 + tn + j;
            const int hh = c >> 6, dd = c & 63;
            out[(((size_t)(bb * H_ + hh)) * N_ + nn) * DK_ + dd] = acc[i][j] + bias[c];
        }
    }
}

// ---------------------------------------------------------------------------
// K2: pairwise box gate. One block per (b, n); thread -> m, m+256.
// wgc[b,h,n,m] = max(relu(geo . WGw[h] + WGb[h]), 1e-6), stored bf16.
// ---------------------------------------------------------------------------
__global__ __launch_bounds__(256) void k_wgc(
    const float* __restrict__ box, const float* __restrict__ WGw,
    const float* __restrict__ WGb, unsigned short* __restrict__ wgc)
{
    const int n = blockIdx.x;
    const int b = blockIdx.y;

    const float4 bn = *(const float4*)&box[(size_t)(b * N_ + n) * 4];
    const float cxn = (bn.x + bn.z) * 0.5f;
    const float cyn = (bn.y + bn.w) * 0.5f;
    const float wn = bn.z - bn.x + 1.0f;
    const float hn = bn.w - bn.y + 1.0f;
    const float lwn = __logf(wn), lhn = __logf(hn);

    for (int mi = 0; mi < 2; ++mi) {
        const int m = threadIdx.x + mi * 256;
        const float4 bm = *(const float4*)&box[(size_t)(b * N_ + m) * 4];
        const float cxm = (bm.x + bm.z) * 0.5f;
        const float cym = (bm.y + bm.w) * 0.5f;
        const float wm = bm.z - bm.x + 1.0f;
        const float hm = bm.w - bm.y + 1.0f;

        float pos[4];
        pos[0] = __logf(fmaxf(fabsf(cxn - cxm) / wn, 1e-3f));
        pos[1] = __logf(fmaxf(fabsf(cyn - cym) / hn, 1e-3f));
        pos[2] = lwn - __logf(wm);
        pos[3] = lhn - __logf(hm);

        float acc[8];
#pragma unroll
        for (int h = 0; h < 8; ++h) acc[h] = WGb[h];

#pragma unroll
        for (int p = 0; p < 4; ++p) {
            const float base = 100.0f * pos[p];
#pragma unroll
            for (int f = 0; f < 8; ++f) {
                const float ang = base * DM_[f];
                const float s = __sinf(ang);
                const float c = __cosf(ang);
#pragma unroll
                for (int h = 0; h < 8; ++h)
                    acc[h] += s * WGw[h * 64 + p * 8 + f] + c * WGw[h * 64 + 32 + p * 8 + f];
            }
        }
#pragma unroll
        for (int h = 0; h < 8; ++h) {
            const size_t idx = (((size_t)(b * H_ + h)) * N_ + n) * N_ + m;
            wgc[idx] = f2bf(fmaxf(acc[h], 1e-6f));
        }
    }
}

// ---------------------------------------------------------------------------
// K3: attention for one (b, h, 32-row tile). softmax(log(wgc)+s) computed as
// wgc * exp(s - rowmax(s)) / sum. fp32 SIMT; scores kept in registers.
// ---------------------------------------------------------------------------
__global__ __launch_bounds__(256) void k_attn(
    const float* __restrict__ qg, const float* __restrict__ kg,
    const float* __restrict__ vg, const unsigned short* __restrict__ wgc,
    float* __restrict__ ao)
{
    const int n0 = blockIdx.x * 32;
    const int h = blockIdx.y;
    const int b = blockIdx.z;
    const int bh = b * H_ + h;

    const float* qp = qg + (size_t)bh * N_ * DK_;
    const float* kp = kg + (size_t)bh * N_ * DK_;
    const float* vp = vg + (size_t)bh * N_ * DK_;

    __shared__ float qls[32][68];
    __shared__ float Sx[32][516];
    __shared__ float red[32][33];
    __shared__ float rowmax_s[32];
    __shared__ float rowsum_s[32];

    const int t = threadIdx.x;

    {   // load q tile (32x64)
        const int r = t >> 3;
        const int c = (t & 7) * 8;
        float4 v0 = *(const float4*)&qp[(size_t)(n0 + r) * DK_ + c];
        float4 v1 = *(const float4*)&qp[(size_t)(n0 + r) * DK_ + c + 4];
        *(float4*)&qls[r][c] = v0;
        *(float4*)&qls[r][c + 4] = v1;
    }
    __syncthreads();

    const int tg = t >> 5;       // 0..7 row-group
    const int tm = t & 31;       // 0..31 m-group
    const int tn4 = tg * 4;

    float sacc[4][16];
#pragma unroll
    for (int i = 0; i < 4; ++i)
#pragma unroll
        for (int j = 0; j < 16; ++j) sacc[i][j] = 0.f;

#pragma unroll
    for (int half = 0; half < 2; ++half) {
        const int mbase = half * 256 + tm * 8;
        for (int c = 0; c < 16; ++c) {
            float4 q4[4];
#pragma unroll
            for (int i = 0; i < 4; ++i) q4[i] = *(const float4*)&qls[tn4 + i][c * 4];
#pragma unroll
            for (int j = 0; j < 8; ++j) {
                const float4 k4 = *(const float4*)&kp[(size_t)(mbase + j) * DK_ + c * 4];
#pragma unroll
                for (int i = 0; i < 4; ++i) {
                    sacc[i][half * 8 + j] += q4[i].x * k4.x + q4[i].y * k4.y +
                                             q4[i].z * k4.z + q4[i].w * k4.w;
                }
            }
        }
    }

    // scale and per-row partial max
#pragma unroll
    for (int i = 0; i < 4; ++i) {
        float mx = -3.4e38f;
#pragma unroll
        for (int j = 0; j < 16; ++j) {
            sacc[i][j] *= 0.125f;
            mx = fmaxf(mx, sacc[i][j]);
        }
        red[tn4 + i][tm] = mx;
    }
    __syncthreads();
    if (t < 32) {
        float mx = red[t][0];
#pragma unroll
        for (int c = 1; c < 32; ++c) mx = fmaxf(mx, red[t][c]);
        rowmax_s[t] = mx;
    }
    __syncthreads();

    // p = wgc * exp(s - rowmax); write to Sx; partial row sums
    const unsigned short* wrow = wgc + (size_t)bh * N_ * N_;
    float psum[4] = {0.f, 0.f, 0.f, 0.f};
#pragma unroll
    for (int i = 0; i < 4; ++i) {
        const int n = n0 + tn4 + i;
        const float rm = rowmax_s[tn4 + i];
#pragma unroll
        for (int half = 0; half < 2; ++half) {
            const int m = half * 256 + tm * 8;
            const uint4 wr = *(const uint4*)&wrow[(size_t)n * N_ + m];
            float w[8];
            w[0] = bf2f((unsigned short)(wr.x));  w[1] = bf2f((unsigned short)(wr.x >> 16));
            w[2] = bf2f((unsigned short)(wr.y));  w[3] = bf2f((unsigned short)(wr.y >> 16));
            w[4] = bf2f((unsigned short)(wr.z));  w[5] = bf2f((unsigned short)(wr.z >> 16));
            w[6] = bf2f((unsigned short)(wr.w));  w[7] = bf2f((unsigned short)(wr.w >> 16));
            float pv[8];
#pragma unroll
            for (int j = 0; j < 8; ++j) {
                pv[j] = w[j] * __expf(sacc[i][half * 8 + j] - rm);
                psum[i] += pv[j];
            }
            *(float4*)&Sx[tn4 + i][m]     = make_float4(pv[0], pv[1], pv[2], pv[3]);
            *(float4*)&Sx[tn4 + i][m + 4] = make_float4(pv[4], pv[5], pv[6], pv[7]);
        }
    }
    __syncthreads();  // red free to reuse
#pragma unroll
    for (int i = 0; i < 4; ++i) red[tn4 + i][tm] = psum[i];
    __syncthreads();
    if (t < 32) {
        float s = 0.f;
#pragma unroll
        for (int c = 0; c < 32; ++c) s += red[t][c];
        rowsum_s[t] = s;
    }
    __syncthreads();

    // PV: wave-uniform n-group, lane = dk. Sx reads are broadcasts.
    const int dk = t & 63;
    const int ng = (t >> 6) * 8;
    float acc[8] = {0.f, 0.f, 0.f, 0.f, 0.f, 0.f, 0.f, 0.f};
    for (int m0 = 0; m0 < 512; m0 += 4) {
        float4 pj[8];
#pragma unroll
        for (int i = 0; i < 8; ++i) pj[i] = *(const float4*)&Sx[ng + i][m0];
#pragma unroll
        for (int j = 0; j < 4; ++j) {
            const float vv = vp[(size_t)(m0 + j) * DK_ + dk];
#pragma unroll
            for (int i = 0; i < 8; ++i) {
                const float p = (j == 0) ? pj[i].x : (j == 1) ? pj[i].y : (j == 2) ? pj[i].z : pj[i].w;
                acc[i] += p * vv;
            }
        }
    }
#pragma unroll
    for (int i = 0; i < 8; ++i) {
        const int n = n0 + ng + i;
        ao[((size_t)(b * N_ + n)) * D_ + h * DK_ + dk] = acc[i] / rowsum_s[ng + i];
    }
}

// ---------------------------------------------------------------------------
// K4: output projection. d_out(4096x512) = AO @ Wo^T + bo. Same tiling as K1.
// ---------------------------------------------------------------------------
__global__ __launch_bounds__(256) void k_oproj(
    const float* __restrict__ AO, const float* __restrict__ Wo,
    const float* __restrict__ bo, float* __restrict__ out)
{
    const int m0 = blockIdx.x * 64;
    const int n0 = blockIdx.y * 64;

    __shared__ float As[16][68];
    __shared__ float Bs[16][68];

    const int t = threadIdx.x;
    const int tm = (t & 15) * 4;
    const int tn = (t >> 4) * 4;
    const int lk = t & 15;
    const int lm4 = (t >> 4) * 4;

    float acc[4][4] = {};

    for (int k0 = 0; k0 < 512; k0 += 16) {
#pragma unroll
        for (int i = 0; i < 4; ++i)
            As[lk][lm4 + i] = AO[(size_t)(m0 + lm4 + i) * 512 + k0 + lk];
#pragma unroll
        for (int i = 0; i < 4; ++i)
            Bs[lk][lm4 + i] = Wo[(size_t)(n0 + lm4 + i) * 512 + k0 + lk];
        __syncthreads();
#pragma unroll
        for (int kk = 0; kk < 16; ++kk) {
            float4 a = *(const float4*)&As[kk][tm];
            float4 b = *(const float4*)&Bs[kk][tn];
            const float av[4] = {a.x, a.y, a.z, a.w};
            const float bv4[4] = {b.x, b.y, b.z, b.w};
#pragma unroll
            for (int i = 0; i < 4; ++i)
#pragma unroll
                for (int j = 0; j < 4; ++j) acc[i][j] += av[i] * bv4[j];
        }
        __syncthreads();
    }

#pragma unroll
    for (int i = 0; i < 4; ++i) {
        const int r = m0 + tm + i;
#pragma unroll
        for (int j = 0; j < 4; ++j) {
            const int c = n0 + tn + j;
            out[(size_t)r * 512 + c] = acc[i][j] + bo[c];
        }
    }
}

extern "C" void kernel_launch(void* const* d_in, const int* in_sizes, int n_in,
                              void* d_out, int out_size, void* d_ws, size_t ws_size,
                              hipStream_t stream) {
    (void)in_sizes; (void)n_in; (void)out_size; (void)ws_size;

    const float* xq  = (const float*)d_in[0];
    const float* xk  = (const float*)d_in[1];
    const float* xv  = (const float*)d_in[2];
    const float* box = (const float*)d_in[3];
    const float* Wq  = (const float*)d_in[4];
    const float* bq  = (const float*)d_in[5];
    const float* Wk  = (const float*)d_in[6];
    const float* bk  = (const float*)d_in[7];
    const float* Wv  = (const float*)d_in[8];
    const float* bv  = (const float*)d_in[9];
    const float* Wo  = (const float*)d_in[10];
    const float* bo  = (const float*)d_in[11];
    const float* WGw = (const float*)d_in[12];
    const float* WGb = (const float*)d_in[13];

    // workspace: q,k,v (f32, 8MB each) | wgc (bf16, 32MB) | ao (f32, 8MB) = 64MB
    float* q = (float*)d_ws;
    float* k = q + 2097152;
    float* v = k + 2097152;
    unsigned short* wgc = (unsigned short*)(v + 2097152);
    float* ao = (float*)((char*)d_ws + 58720256);

    k_proj<<<dim3(64, 8, 3), 256, 0, stream>>>(xq, xk, xv, Wq, Wk, Wv, bq, bk, bv, q, k, v);
    k_wgc<<<dim3(512, 8), 256, 0, stream>>>(box, WGw, WGb, wgc);
    k_attn<<<dim3(16, 8, 8), 256, 0, stream>>>(q, k, v, wgc, ao);
    k_oproj<<<dim3(64, 8), 256, 0, stream>>>(ao, Wo, bo, (float*)d_out);
}

// Round 2
// 339.484 us; speedup vs baseline: 2.0718x; 2.0718x over previous
//
#include <hip/hip_runtime.h>
#include <hip/hip_bf16.h>

#define B_ 8
#define N_ 512
#define D_ 512
#define H_ 8
#define DK_ 64

// 1000^(-f/8), f=0..7 (double-evaluated, f32-rounded)
__device__ constexpr float DMc[8] = {
    1.0f, 0.42169650342905464f, 0.1778279410038923f, 0.07498942093324559f,
    0.03162277660168379f, 0.013335214321633241f, 0.005623413251903491f,
    0.0023713737056616554f};

__device__ inline float bf2f(unsigned short u) {
    unsigned int x = ((unsigned int)u) << 16;
    return __uint_as_float(x);
}

typedef __attribute__((ext_vector_type(8))) short bf8v;
typedef __attribute__((ext_vector_type(4))) float f4v;

union AFrag { bf8v v; unsigned int u[4]; };

__device__ inline unsigned int cvt_pk_bf16(float a, float b) {
    unsigned int r;
    asm("v_cvt_pk_bf16_f32 %0, %1, %2" : "=v"(r) : "v"(a), "v"(b));
    return r;  // bits[15:0]=bf16(a), bits[31:16]=bf16(b)
}

// ---------------------------------------------------------------------------
// K1: fused Q/K/V projection. C(4096x512) = X(4096x512) @ W^T + b, written as
// (B,H,N,DK). blockIdx.z selects q/k/v. 64x64 tile, 4x4 per thread, fp32.
// ---------------------------------------------------------------------------
__global__ __launch_bounds__(256) void k_proj(
    const float* __restrict__ Xq, const float* __restrict__ Xk, const float* __restrict__ Xv,
    const float* __restrict__ Wq, const float* __restrict__ Wk, const float* __restrict__ Wv,
    const float* __restrict__ bq, const float* __restrict__ bk, const float* __restrict__ bv,
    float* __restrict__ oq, float* __restrict__ ok, float* __restrict__ ov)
{
    const int z = blockIdx.z;
    const float* X = (z == 0) ? Xq : (z == 1) ? Xk : Xv;
    const float* W = (z == 0) ? Wq : (z == 1) ? Wk : Wv;
    const float* bias = (z == 0) ? bq : (z == 1) ? bk : bv;
    float* out = (z == 0) ? oq : (z == 1) ? ok : ov;

    const int m0 = blockIdx.x * 64;   // rows (B*N flat)
    const int n0 = blockIdx.y * 64;   // cols (D)

    __shared__ float As[16][68];
    __shared__ float Bs[16][68];

    const int t = threadIdx.x;
    const int tm = (t & 15) * 4;
    const int tn = (t >> 4) * 4;
    const int lk = t & 15;
    const int lm4 = (t >> 4) * 4;

    float acc[4][4] = {};

    for (int k0 = 0; k0 < 512; k0 += 16) {
#pragma unroll
        for (int i = 0; i < 4; ++i)
            As[lk][lm4 + i] = X[(size_t)(m0 + lm4 + i) * 512 + k0 + lk];
#pragma unroll
        for (int i = 0; i < 4; ++i)
            Bs[lk][lm4 + i] = W[(size_t)(n0 + lm4 + i) * 512 + k0 + lk];
        __syncthreads();
#pragma unroll
        for (int kk = 0; kk < 16; ++kk) {
            float4 a = *(const float4*)&As[kk][tm];
            float4 b = *(const float4*)&Bs[kk][tn];
            const float av[4] = {a.x, a.y, a.z, a.w};
            const float bv4[4] = {b.x, b.y, b.z, b.w};
#pragma unroll
            for (int i = 0; i < 4; ++i)
#pragma unroll
                for (int j = 0; j < 4; ++j) acc[i][j] += av[i] * bv4[j];
        }
        __syncthreads();
    }

#pragma unroll
    for (int i = 0; i < 4; ++i) {
        const int r = m0 + tm + i;
        const int bb = r >> 9, nn = r & 511;
#pragma unroll
        for (int j = 0; j < 4; ++j) {
            const int c = n0 + tn + j;
            const int hh = c >> 6, dd = c & 63;
            out[(((size_t)(bb * H_ + hh)) * N_ + nn) * DK_ + dd] = acc[i][j] + bias[c];
        }
    }
}

// ---------------------------------------------------------------------------
// K2 (v2): pairwise box gate via MFMA.
// Block = (b, n), 256 threads = 4 waves. Per-box table (cx,cy,lw,lh) staged in
// LDS once per block. Each wave computes a 16(m) x 8(h) gate tile per iter:
// lane group p (lane>>4) builds pos[p] for row m=lane&15, 8 angles, sin->A1,
// cos->A2 (bf16), two chained mfma_f32_16x16x32_bf16 against bf16 WGw.
// wgc[b,h,n,m] = max(acc + WGb[h], 1e-6) stored bf16 (4 consecutive m / lane).
// ---------------------------------------------------------------------------
__global__ __launch_bounds__(256) void k_wgc(
    const float* __restrict__ box, const float* __restrict__ WGw,
    const float* __restrict__ WGb, unsigned short* __restrict__ wgc)
{
    const int n = blockIdx.x;
    const int b = blockIdx.y;

    __shared__ float S[4][520];   // [p][m] : cx, cy, lw, lh ; 520 pad -> 2-way banks (free)

    const int t = threadIdx.x;

    for (int mi = t; mi < 512; mi += 256) {
        const float4 bx = *(const float4*)&box[(size_t)(b * N_ + mi) * 4];
        S[0][mi] = (bx.x + bx.z) * 0.5f;
        S[1][mi] = (bx.y + bx.w) * 0.5f;
        S[2][mi] = __logf(bx.z - bx.x + 1.0f);
        S[3][mi] = __logf(bx.w - bx.y + 1.0f);
    }

    // per-n scalars (computed redundantly by every thread; broadcast loads)
    const float4 bn = *(const float4*)&box[(size_t)(b * N_ + n) * 4];
    const float wn = bn.z - bn.x + 1.0f;
    const float hn = bn.w - bn.y + 1.0f;
    const float rwn = 1.0f / wn;
    const float rhn = 1.0f / hn;
    const float cxn = (bn.x + bn.z) * 0.5f;
    const float cyn = (bn.y + bn.w) * 0.5f;
    const float lwn = __logf(wn);
    const float lhn = __logf(hn);

    const int lane = t & 63;
    const int col = lane & 15;     // A row (m offset) / C col (head)
    const int grp = lane >> 4;     // A k-group = pos index p / C row group
    const int w = t >> 6;          // wave 0..3

    // B fragments: B[k, c] = WGw[c, g] with g = k (sin) / g = 32+k (cos)
    AFrag bs, bc;
    if (col < 8) {
        const float* wr = WGw + col * 64 + grp * 8;
#pragma unroll
        for (int j = 0; j < 4; ++j) {
            bs.u[j] = cvt_pk_bf16(wr[2 * j], wr[2 * j + 1]);
            bc.u[j] = cvt_pk_bf16(wr[32 + 2 * j], wr[32 + 2 * j + 1]);
        }
    } else {
#pragma unroll
        for (int j = 0; j < 4; ++j) { bs.u[j] = 0u; bc.u[j] = 0u; }
    }
    const float bias = (col < 8) ? WGb[col] : 0.0f;

    const float dn = (grp == 0) ? cxn : (grp == 1) ? cyn : (grp == 2) ? lwn : lhn;
    const float rA = (grp == 0) ? rwn : rhn;

    unsigned short* outb = (col < 8)
        ? wgc + ((size_t)(b * H_ + col) * N_ + n) * N_ : wgc;

    __syncthreads();

    for (int mt = 0; mt < 8; ++mt) {
        const int m0 = mt * 64 + w * 16;

        // pos for this lane's (row m, component p)
        const float sv = S[grp][m0 + col];
        const float diff = dn - sv;
        const float posA = __logf(fmaxf(fabsf(diff) * rA, 1e-3f));
        const float pos = (grp < 2) ? posA : diff;   // p2/p3: lwn-lwm / lhn-lhm
        const float p100 = 100.0f * pos;

        float sn[8], cs[8];
#pragma unroll
        for (int j = 0; j < 8; ++j) {
            const float ang = p100 * DMc[j];
            sn[j] = __sinf(ang);
            cs[j] = __cosf(ang);
        }
        AFrag as_, ac_;
#pragma unroll
        for (int j = 0; j < 4; ++j) {
            as_.u[j] = cvt_pk_bf16(sn[2 * j], sn[2 * j + 1]);
            ac_.u[j] = cvt_pk_bf16(cs[2 * j], cs[2 * j + 1]);
        }

        f4v acc = __builtin_amdgcn_mfma_f32_16x16x32_bf16(
            as_.v, bs.v, (f4v){0.f, 0.f, 0.f, 0.f}, 0, 0, 0);
        acc = __builtin_amdgcn_mfma_f32_16x16x32_bf16(ac_.v, bc.v, acc, 0, 0, 0);

        if (col < 8) {
            const int mrow = m0 + grp * 4;   // C rows: 4 consecutive m
            const float v0 = fmaxf(acc[0] + bias, 1e-6f);
            const float v1 = fmaxf(acc[1] + bias, 1e-6f);
            const float v2 = fmaxf(acc[2] + bias, 1e-6f);
            const float v3 = fmaxf(acc[3] + bias, 1e-6f);
            uint2 pk;
            pk.x = cvt_pk_bf16(v0, v1);
            pk.y = cvt_pk_bf16(v2, v3);
            *(uint2*)&outb[mrow] = pk;
        }
    }
}

// ---------------------------------------------------------------------------
// K3: attention for one (b, h, 32-row tile). softmax(log(wgc)+s) computed as
// wgc * exp(s - rowmax(s)) / sum. fp32 SIMT; scores kept in registers.
// ---------------------------------------------------------------------------
__global__ __launch_bounds__(256) void k_attn(
    const float* __restrict__ qg, const float* __restrict__ kg,
    const float* __restrict__ vg, const unsigned short* __restrict__ wgc,
    float* __restrict__ ao)
{
    const int n0 = blockIdx.x * 32;
    const int h = blockIdx.y;
    const int b = blockIdx.z;
    const int bh = b * H_ + h;

    const float* qp = qg + (size_t)bh * N_ * DK_;
    const float* kp = kg + (size_t)bh * N_ * DK_;
    const float* vp = vg + (size_t)bh * N_ * DK_;

    __shared__ float qls[32][68];
    __shared__ float Sx[32][516];
    __shared__ float red[32][33];
    __shared__ float rowmax_s[32];
    __shared__ float rowsum_s[32];

    const int t = threadIdx.x;

    {   // load q tile (32x64)
        const int r = t >> 3;
        const int c = (t & 7) * 8;
        float4 v0 = *(const float4*)&qp[(size_t)(n0 + r) * DK_ + c];
        float4 v1 = *(const float4*)&qp[(size_t)(n0 + r) * DK_ + c + 4];
        *(float4*)&qls[r][c] = v0;
        *(float4*)&qls[r][c + 4] = v1;
    }
    __syncthreads();

    const int tg = t >> 5;       // 0..7 row-group
    const int tm = t & 31;       // 0..31 m-group
    const int tn4 = tg * 4;

    float sacc[4][16];
#pragma unroll
    for (int i = 0; i < 4; ++i)
#pragma unroll
        for (int j = 0; j < 16; ++j) sacc[i][j] = 0.f;

#pragma unroll
    for (int half = 0; half < 2; ++half) {
        const int mbase = half * 256 + tm * 8;
        for (int c = 0; c < 16; ++c) {
            float4 q4[4];
#pragma unroll
            for (int i = 0; i < 4; ++i) q4[i] = *(const float4*)&qls[tn4 + i][c * 4];
#pragma unroll
            for (int j = 0; j < 8; ++j) {
                const float4 k4 = *(const float4*)&kp[(size_t)(mbase + j) * DK_ + c * 4];
#pragma unroll
                for (int i = 0; i < 4; ++i) {
                    sacc[i][half * 8 + j] += q4[i].x * k4.x + q4[i].y * k4.y +
                                             q4[i].z * k4.z + q4[i].w * k4.w;
                }
            }
        }
    }

    // scale and per-row partial max
#pragma unroll
    for (int i = 0; i < 4; ++i) {
        float mx = -3.4e38f;
#pragma unroll
        for (int j = 0; j < 16; ++j) {
            sacc[i][j] *= 0.125f;
            mx = fmaxf(mx, sacc[i][j]);
        }
        red[tn4 + i][tm] = mx;
    }
    __syncthreads();
    if (t < 32) {
        float mx = red[t][0];
#pragma unroll
        for (int c = 1; c < 32; ++c) mx = fmaxf(mx, red[t][c]);
        rowmax_s[t] = mx;
    }
    __syncthreads();

    // p = wgc * exp(s - rowmax); write to Sx; partial row sums
    const unsigned short* wrow = wgc + (size_t)bh * N_ * N_;
    float psum[4] = {0.f, 0.f, 0.f, 0.f};
#pragma unroll
    for (int i = 0; i < 4; ++i) {
        const int n = n0 + tn4 + i;
        const float rm = rowmax_s[tn4 + i];
#pragma unroll
        for (int half = 0; half < 2; ++half) {
            const int m = half * 256 + tm * 8;
            const uint4 wr = *(const uint4*)&wrow[(size_t)n * N_ + m];
            float w[8];
            w[0] = bf2f((unsigned short)(wr.x));  w[1] = bf2f((unsigned short)(wr.x >> 16));
            w[2] = bf2f((unsigned short)(wr.y));  w[3] = bf2f((unsigned short)(wr.y >> 16));
            w[4] = bf2f((unsigned short)(wr.z));  w[5] = bf2f((unsigned short)(wr.z >> 16));
            w[6] = bf2f((unsigned short)(wr.w));  w[7] = bf2f((unsigned short)(wr.w >> 16));
            float pv[8];
#pragma unroll
            for (int j = 0; j < 8; ++j) {
                pv[j] = w[j] * __expf(sacc[i][half * 8 + j] - rm);
                psum[i] += pv[j];
            }
            *(float4*)&Sx[tn4 + i][m]     = make_float4(pv[0], pv[1], pv[2], pv[3]);
            *(float4*)&Sx[tn4 + i][m + 4] = make_float4(pv[4], pv[5], pv[6], pv[7]);
        }
    }
    __syncthreads();  // red free to reuse
#pragma unroll
    for (int i = 0; i < 4; ++i) red[tn4 + i][tm] = psum[i];
    __syncthreads();
    if (t < 32) {
        float s = 0.f;
#pragma unroll
        for (int c = 0; c < 32; ++c) s += red[t][c];
        rowsum_s[t] = s;
    }
    __syncthreads();

    // PV: wave-uniform n-group, lane = dk. Sx reads are broadcasts.
    const int dk = t & 63;
    const int ng = (t >> 6) * 8;
    float acc[8] = {0.f, 0.f, 0.f, 0.f, 0.f, 0.f, 0.f, 0.f};
    for (int m0 = 0; m0 < 512; m0 += 4) {
        float4 pj[8];
#pragma unroll
        for (int i = 0; i < 8; ++i) pj[i] = *(const float4*)&Sx[ng + i][m0];
#pragma unroll
        for (int j = 0; j < 4; ++j) {
            const float vv = vp[(size_t)(m0 + j) * DK_ + dk];
#pragma unroll
            for (int i = 0; i < 8; ++i) {
                const float p = (j == 0) ? pj[i].x : (j == 1) ? pj[i].y : (j == 2) ? pj[i].z : pj[i].w;
                acc[i] += p * vv;
            }
        }
    }
#pragma unroll
    for (int i = 0; i < 8; ++i) {
        const int n = n0 + ng + i;
        ao[((size_t)(b * N_ + n)) * D_ + h * DK_ + dk] = acc[i] / rowsum_s[ng + i];
    }
}

// ---------------------------------------------------------------------------
// K4: output projection. d_out(4096x512) = AO @ Wo^T + bo. Same tiling as K1.
// ---------------------------------------------------------------------------
__global__ __launch_bounds__(256) void k_oproj(
    const float* __restrict__ AO, const float* __restrict__ Wo,
    const float* __restrict__ bo, float* __restrict__ out)
{
    const int m0 = blockIdx.x * 64;
    const int n0 = blockIdx.y * 64;

    __shared__ float As[16][68];
    __shared__ float Bs[16][68];

    const int t = threadIdx.x;
    const int tm = (t & 15) * 4;
    const int tn = (t >> 4) * 4;
    const int lk = t & 15;
    const int lm4 = (t >> 4) * 4;

    float acc[4][4] = {};

    for (int k0 = 0; k0 < 512; k0 += 16) {
#pragma unroll
        for (int i = 0; i < 4; ++i)
            As[lk][lm4 + i] = AO[(size_t)(m0 + lm4 + i) * 512 + k0 + lk];
#pragma unroll
        for (int i = 0; i < 4; ++i)
            Bs[lk][lm4 + i] = Wo[(size_t)(n0 + lm4 + i) * 512 + k0 + lk];
        __syncthreads();
#pragma unroll
        for (int kk = 0; kk < 16; ++kk) {
            float4 a = *(const float4*)&As[kk][tm];
            float4 b = *(const float4*)&Bs[kk][tn];
            const float av[4] = {a.x, a.y, a.z, a.w};
            const float bv4[4] = {b.x, b.y, b.z, b.w};
#pragma unroll
            for (int i = 0; i < 4; ++i)
#pragma unroll
                for (int j = 0; j < 4; ++j) acc[i][j] += av[i] * bv4[j];
        }
        __syncthreads();
    }

#pragma unroll
    for (int i = 0; i < 4; ++i) {
        const int r = m0 + tm + i;
#pragma unroll
        for (int j = 0; j < 4; ++j) {
            const int c = n0 + tn + j;
            out[(size_t)r * 512 + c] = acc[i][j] + bo[c];
        }
    }
}

extern "C" void kernel_launch(void* const* d_in, const int* in_sizes, int n_in,
                              void* d_out, int out_size, void* d_ws, size_t ws_size,
                              hipStream_t stream) {
    (void)in_sizes; (void)n_in; (void)out_size; (void)ws_size;

    const float* xq  = (const float*)d_in[0];
    const float* xk  = (const float*)d_in[1];
    const float* xv  = (const float*)d_in[2];
    const float* box = (const float*)d_in[3];
    const float* Wq  = (const float*)d_in[4];
    const float* bq  = (const float*)d_in[5];
    const float* Wk  = (const float*)d_in[6];
    const float* bk  = (const float*)d_in[7];
    const float* Wv  = (const float*)d_in[8];
    const float* bv  = (const float*)d_in[9];
    const float* Wo  = (const float*)d_in[10];
    const float* bo  = (const float*)d_in[11];
    const float* WGw = (const float*)d_in[12];
    const float* WGb = (const float*)d_in[13];

    // workspace: q,k,v (f32, 8MB each) | wgc (bf16, 32MB) | ao (f32, 8MB) = 64MB
    float* q = (float*)d_ws;
    float* k = q + 2097152;
    float* v = k + 2097152;
    unsigned short* wgc = (unsigned short*)(v + 2097152);
    float* ao = (float*)((char*)d_ws + 58720256);

    k_proj<<<dim3(64, 8, 3), 256, 0, stream>>>(xq, xk, xv, Wq, Wk, Wv, bq, bk, bv, q, k, v);
    k_wgc<<<dim3(512, 8), 256, 0, stream>>>(box, WGw, WGb, wgc);
    k_attn<<<dim3(16, 8, 8), 256, 0, stream>>>(q, k, v, wgc, ao);
    k_oproj<<<dim3(64, 8), 256, 0, stream>>>(ao, Wo, bo, (float*)d_out);
}

// Round 3
// 226.990 us; speedup vs baseline: 3.0986x; 1.4956x over previous
//
#include <hip/hip_runtime.h>
#include <hip/hip_bf16.h>

#define B_ 8
#define N_ 512
#define D_ 512
#define H_ 8
#define DK_ 64

// 1000^(-f/8), f=0..7 (double-evaluated, f32-rounded)
__device__ constexpr float DMc[8] = {
    1.0f, 0.42169650342905464f, 0.1778279410038923f, 0.07498942093324559f,
    0.03162277660168379f, 0.013335214321633241f, 0.005623413251903491f,
    0.0023713737056616554f};

__device__ inline float bf2f(unsigned short u) {
    unsigned int x = ((unsigned int)u) << 16;
    return __uint_as_float(x);
}

typedef __attribute__((ext_vector_type(8))) short bf8v;
typedef __attribute__((ext_vector_type(4))) float f4v;

union AFrag { bf8v v; unsigned int u[4]; uint2 d[2]; };

__device__ inline unsigned int cvt_pk_bf16(float a, float b) {
    unsigned int r;
    asm("v_cvt_pk_bf16_f32 %0, %1, %2" : "=v"(r) : "v"(a), "v"(b));
    return r;  // bits[15:0]=bf16(a), bits[31:16]=bf16(b)
}

// ---------------------------------------------------------------------------
// K1: fused Q/K/V projection. C(4096x512) = X(4096x512) @ W^T + b. fp32 SIMT
// compute; epilogue emits bf16: q/8 and k as (B,H,N,DK), v transposed as
// (B,H,DK,N). blockIdx.z selects q/k/v.
// ---------------------------------------------------------------------------
__global__ __launch_bounds__(256) void k_proj(
    const float* __restrict__ Xq, const float* __restrict__ Xk, const float* __restrict__ Xv,
    const float* __restrict__ Wq, const float* __restrict__ Wk, const float* __restrict__ Wv,
    const float* __restrict__ bq, const float* __restrict__ bk, const float* __restrict__ bv,
    unsigned short* __restrict__ oq, unsigned short* __restrict__ ok,
    unsigned short* __restrict__ ov)
{
    const int z = blockIdx.z;
    const float* X = (z == 0) ? Xq : (z == 1) ? Xk : Xv;
    const float* W = (z == 0) ? Wq : (z == 1) ? Wk : Wv;
    const float* bias = (z == 0) ? bq : (z == 1) ? bk : bv;
    unsigned short* out = (z == 0) ? oq : (z == 1) ? ok : ov;

    const int m0 = blockIdx.x * 64;   // rows (B*N flat)
    const int n0 = blockIdx.y * 64;   // cols (D)

    __shared__ float As[16][68];
    __shared__ float Bs[16][68];

    const int t = threadIdx.x;
    const int tm = (t & 15) * 4;
    const int tn = (t >> 4) * 4;
    const int lk = t & 15;
    const int lm4 = (t >> 4) * 4;

    float acc[4][4] = {};

    for (int k0 = 0; k0 < 512; k0 += 16) {
#pragma unroll
        for (int i = 0; i < 4; ++i)
            As[lk][lm4 + i] = X[(size_t)(m0 + lm4 + i) * 512 + k0 + lk];
#pragma unroll
        for (int i = 0; i < 4; ++i)
            Bs[lk][lm4 + i] = W[(size_t)(n0 + lm4 + i) * 512 + k0 + lk];
        __syncthreads();
#pragma unroll
        for (int kk = 0; kk < 16; ++kk) {
            float4 a = *(const float4*)&As[kk][tm];
            float4 b = *(const float4*)&Bs[kk][tn];
            const float av[4] = {a.x, a.y, a.z, a.w};
            const float bv4[4] = {b.x, b.y, b.z, b.w};
#pragma unroll
            for (int i = 0; i < 4; ++i)
#pragma unroll
                for (int j = 0; j < 4; ++j) acc[i][j] += av[i] * bv4[j];
        }
        __syncthreads();
    }

    if (z < 2) {
        const float sc = (z == 0) ? 0.125f : 1.0f;   // fold 1/sqrt(DK) into q
#pragma unroll
        for (int i = 0; i < 4; ++i) {
            const int r = m0 + tm + i;
            const int bb = r >> 9, nn = r & 511;
            const int c0 = n0 + tn;
            const int hh = c0 >> 6, dd = c0 & 63;
            uint2 pk2;
            pk2.x = cvt_pk_bf16((acc[i][0] + bias[c0]) * sc, (acc[i][1] + bias[c0 + 1]) * sc);
            pk2.y = cvt_pk_bf16((acc[i][2] + bias[c0 + 2]) * sc, (acc[i][3] + bias[c0 + 3]) * sc);
            *(uint2*)&out[(((size_t)(bb * H_ + hh)) * N_ + nn) * DK_ + dd] = pk2;
        }
    } else {
        // v transposed: (B,H,DK,N)
#pragma unroll
        for (int j = 0; j < 4; ++j) {
            const int c = n0 + tn + j;
            const int hh = c >> 6, dd = c & 63;
            const int r0 = m0 + tm;
            const int bb = r0 >> 9, nn = r0 & 511;
            const float bv2 = bias[c];
            uint2 pk2;
            pk2.x = cvt_pk_bf16(acc[0][j] + bv2, acc[1][j] + bv2);
            pk2.y = cvt_pk_bf16(acc[2][j] + bv2, acc[3][j] + bv2);
            *(uint2*)&out[(((size_t)(bb * H_ + hh)) * DK_ + dd) * N_ + nn] = pk2;
        }
    }
}

// ---------------------------------------------------------------------------
// K2: pairwise box gate via MFMA (unchanged from round 2).
// ---------------------------------------------------------------------------
__global__ __launch_bounds__(256) void k_wgc(
    const float* __restrict__ box, const float* __restrict__ WGw,
    const float* __restrict__ WGb, unsigned short* __restrict__ wgc)
{
    const int n = blockIdx.x;
    const int b = blockIdx.y;

    __shared__ float S[4][520];

    const int t = threadIdx.x;

    for (int mi = t; mi < 512; mi += 256) {
        const float4 bx = *(const float4*)&box[(size_t)(b * N_ + mi) * 4];
        S[0][mi] = (bx.x + bx.z) * 0.5f;
        S[1][mi] = (bx.y + bx.w) * 0.5f;
        S[2][mi] = __logf(bx.z - bx.x + 1.0f);
        S[3][mi] = __logf(bx.w - bx.y + 1.0f);
    }

    const float4 bn = *(const float4*)&box[(size_t)(b * N_ + n) * 4];
    const float wn = bn.z - bn.x + 1.0f;
    const float hn = bn.w - bn.y + 1.0f;
    const float rwn = 1.0f / wn;
    const float rhn = 1.0f / hn;
    const float cxn = (bn.x + bn.z) * 0.5f;
    const float cyn = (bn.y + bn.w) * 0.5f;
    const float lwn = __logf(wn);
    const float lhn = __logf(hn);

    const int lane = t & 63;
    const int col = lane & 15;
    const int grp = lane >> 4;
    const int w = t >> 6;

    AFrag bs, bc;
    if (col < 8) {
        const float* wr = WGw + col * 64 + grp * 8;
#pragma unroll
        for (int j = 0; j < 4; ++j) {
            bs.u[j] = cvt_pk_bf16(wr[2 * j], wr[2 * j + 1]);
            bc.u[j] = cvt_pk_bf16(wr[32 + 2 * j], wr[32 + 2 * j + 1]);
        }
    } else {
#pragma unroll
        for (int j = 0; j < 4; ++j) { bs.u[j] = 0u; bc.u[j] = 0u; }
    }
    const float bias = (col < 8) ? WGb[col] : 0.0f;

    const float dn = (grp == 0) ? cxn : (grp == 1) ? cyn : (grp == 2) ? lwn : lhn;
    const float rA = (grp == 0) ? rwn : rhn;

    unsigned short* outb = (col < 8)
        ? wgc + ((size_t)(b * H_ + col) * N_ + n) * N_ : wgc;

    __syncthreads();

    for (int mt = 0; mt < 8; ++mt) {
        const int m0 = mt * 64 + w * 16;

        const float sv = S[grp][m0 + col];
        const float diff = dn - sv;
        const float posA = __logf(fmaxf(fabsf(diff) * rA, 1e-3f));
        const float pos = (grp < 2) ? posA : diff;
        const float p100 = 100.0f * pos;

        float sn[8], cs[8];
#pragma unroll
        for (int j = 0; j < 8; ++j) {
            const float ang = p100 * DMc[j];
            sn[j] = __sinf(ang);
            cs[j] = __cosf(ang);
        }
        AFrag as_, ac_;
#pragma unroll
        for (int j = 0; j < 4; ++j) {
            as_.u[j] = cvt_pk_bf16(sn[2 * j], sn[2 * j + 1]);
            ac_.u[j] = cvt_pk_bf16(cs[2 * j], cs[2 * j + 1]);
        }

        f4v acc = __builtin_amdgcn_mfma_f32_16x16x32_bf16(
            as_.v, bs.v, (f4v){0.f, 0.f, 0.f, 0.f}, 0, 0, 0);
        acc = __builtin_amdgcn_mfma_f32_16x16x32_bf16(ac_.v, bc.v, acc, 0, 0, 0);

        if (col < 8) {
            const int mrow = m0 + grp * 4;
            const float v0 = fmaxf(acc[0] + bias, 1e-6f);
            const float v1 = fmaxf(acc[1] + bias, 1e-6f);
            const float v2 = fmaxf(acc[2] + bias, 1e-6f);
            const float v3 = fmaxf(acc[3] + bias, 1e-6f);
            uint2 pk;
            pk.x = cvt_pk_bf16(v0, v1);
            pk.y = cvt_pk_bf16(v2, v3);
            *(uint2*)&outb[mrow] = pk;
        }
    }
}

// ---------------------------------------------------------------------------
// K3 (v2): MFMA attention, no LDS. Block = 4 independent waves; wave owns 16
// q-rows of one (b,h). Swapped QK^T (A=K, B=Q) -> lane holds S[q=lane&15]
// [m=16t+4g+reg]. Gate+exp in-register; P packs directly into PV A-frags
// (split-4+4 k-mapping). PV B-frags from v_t (B,H,DK,N). Out /= rowsum.
// ---------------------------------------------------------------------------
__global__ __launch_bounds__(256, 2) void k_attn(
    const unsigned short* __restrict__ qb_g, const unsigned short* __restrict__ kb_g,
    const unsigned short* __restrict__ vt_g, const unsigned short* __restrict__ wgc,
    float* __restrict__ ao)
{
    // XCD-chunked bijective swizzle: hw bids with same (bid&7) share an XCD
    // and get 64 consecutive logical blocks = 8 heads' worth of K/V (1MB, L2-fit).
    const int bid = blockIdx.x;
    const int lid = ((bid & 7) << 6) | (bid >> 3);
    const int qt = lid & 7;
    const int h = (lid >> 3) & 7;
    const int b = lid >> 6;
    const int bh = b * H_ + h;

    const int t = threadIdx.x;
    const int lane = t & 63;
    const int w = t >> 6;
    const int cl = lane & 15;     // S phase: q-col ; PV phase: d-col
    const int g = lane >> 4;

    const int q_row = qt * 64 + w * 16 + cl;

    // Q B-frags: elem j<4 -> dk = dkt*32 + 4g + j ; j>=4 -> +16
    AFrag qf[2];
    {
        const unsigned short* qrow = qb_g + ((size_t)bh * N_ + q_row) * DK_;
#pragma unroll
        for (int dkt = 0; dkt < 2; ++dkt) {
            qf[dkt].d[0] = *(const uint2*)&qrow[dkt * 32 + 4 * g];
            qf[dkt].d[1] = *(const uint2*)&qrow[dkt * 32 + 16 + 4 * g];
        }
    }

    // QK^T: 32 m-tiles of 16
    f4v sv[32];
    const unsigned short* kbase = kb_g + (size_t)bh * N_ * DK_;
#pragma unroll
    for (int mt = 0; mt < 32; ++mt) {
        const unsigned short* krow = kbase + (size_t)(mt * 16 + cl) * DK_;
        AFrag a0, a1;
        a0.d[0] = *(const uint2*)&krow[4 * g];
        a0.d[1] = *(const uint2*)&krow[16 + 4 * g];
        a1.d[0] = *(const uint2*)&krow[32 + 4 * g];
        a1.d[1] = *(const uint2*)&krow[48 + 4 * g];
        f4v acc = __builtin_amdgcn_mfma_f32_16x16x32_bf16(
            a0.v, qf[0].v, (f4v){0.f, 0.f, 0.f, 0.f}, 0, 0, 0);
        sv[mt] = __builtin_amdgcn_mfma_f32_16x16x32_bf16(a1.v, qf[1].v, acc, 0, 0, 0);
    }

    // p = wgc * exp(s); row-sum; pack P into PV A-frags.
    // A-frag(T): elems 0-3 = m=32T+4g+j (tile 2T), elems 4-7 = m=32T+16+4g+j (tile 2T+1).
    const unsigned short* wrow = wgc + ((size_t)bh * N_ + q_row) * N_;
    float rsum = 0.f;
    AFrag pa[16];
#pragma unroll
    for (int T = 0; T < 16; ++T) {
        float p[8];
#pragma unroll
        for (int hf = 0; hf < 2; ++hf) {
            const int mt = 2 * T + hf;
            const uint2 wg2 = *(const uint2*)&wrow[mt * 16 + 4 * g];
            const float w0 = bf2f((unsigned short)wg2.x);
            const float w1 = bf2f((unsigned short)(wg2.x >> 16));
            const float w2 = bf2f((unsigned short)wg2.y);
            const float w3 = bf2f((unsigned short)(wg2.y >> 16));
            p[hf * 4 + 0] = w0 * __expf(sv[mt][0]);
            p[hf * 4 + 1] = w1 * __expf(sv[mt][1]);
            p[hf * 4 + 2] = w2 * __expf(sv[mt][2]);
            p[hf * 4 + 3] = w3 * __expf(sv[mt][3]);
            rsum += p[hf * 4 + 0] + p[hf * 4 + 1] + p[hf * 4 + 2] + p[hf * 4 + 3];
        }
        pa[T].u[0] = cvt_pk_bf16(p[0], p[1]);
        pa[T].u[1] = cvt_pk_bf16(p[2], p[3]);
        pa[T].u[2] = cvt_pk_bf16(p[4], p[5]);
        pa[T].u[3] = cvt_pk_bf16(p[6], p[7]);
    }
    rsum += __shfl_xor(rsum, 16);
    rsum += __shfl_xor(rsum, 32);

    // PV: O[q][d] = sum_m P[q][m] V_T[d][m]
    f4v oacc[4] = {(f4v){0.f, 0.f, 0.f, 0.f}, (f4v){0.f, 0.f, 0.f, 0.f},
                   (f4v){0.f, 0.f, 0.f, 0.f}, (f4v){0.f, 0.f, 0.f, 0.f}};
    const unsigned short* vbase = vt_g + (size_t)bh * DK_ * N_;
#pragma unroll
    for (int T = 0; T < 16; ++T) {
#pragma unroll
        for (int db = 0; db < 4; ++db) {
            const unsigned short* vrow = vbase + (size_t)(db * 16 + cl) * N_ + T * 32;
            AFrag vb;
            vb.d[0] = *(const uint2*)&vrow[4 * g];
            vb.d[1] = *(const uint2*)&vrow[16 + 4 * g];
            oacc[db] = __builtin_amdgcn_mfma_f32_16x16x32_bf16(pa[T].v, vb.v, oacc[db], 0, 0, 0);
        }
    }

    // epilogue: O row = q = 4g+reg, col = d = db*16 + cl. Normalize by rowsum.
    float rinv[4];
#pragma unroll
    for (int r = 0; r < 4; ++r) rinv[r] = 1.0f / __shfl(rsum, 4 * g + r);
    const int q0w = qt * 64 + w * 16;
#pragma unroll
    for (int db = 0; db < 4; ++db) {
#pragma unroll
        for (int r = 0; r < 4; ++r) {
            const int qq = q0w + 4 * g + r;
            ao[((size_t)(b * N_ + qq)) * D_ + h * DK_ + db * 16 + cl] = oacc[db][r] * rinv[r];
        }
    }
}

// ---------------------------------------------------------------------------
// K4: output projection. d_out(4096x512) = AO @ Wo^T + bo (unchanged).
// ---------------------------------------------------------------------------
__global__ __launch_bounds__(256) void k_oproj(
    const float* __restrict__ AO, const float* __restrict__ Wo,
    const float* __restrict__ bo, float* __restrict__ out)
{
    const int m0 = blockIdx.x * 64;
    const int n0 = blockIdx.y * 64;

    __shared__ float As[16][68];
    __shared__ float Bs[16][68];

    const int t = threadIdx.x;
    const int tm = (t & 15) * 4;
    const int tn = (t >> 4) * 4;
    const int lk = t & 15;
    const int lm4 = (t >> 4) * 4;

    float acc[4][4] = {};

    for (int k0 = 0; k0 < 512; k0 += 16) {
#pragma unroll
        for (int i = 0; i < 4; ++i)
            As[lk][lm4 + i] = AO[(size_t)(m0 + lm4 + i) * 512 + k0 + lk];
#pragma unroll
        for (int i = 0; i < 4; ++i)
            Bs[lk][lm4 + i] = Wo[(size_t)(n0 + lm4 + i) * 512 + k0 + lk];
        __syncthreads();
#pragma unroll
        for (int kk = 0; kk < 16; ++kk) {
            float4 a = *(const float4*)&As[kk][tm];
            float4 b = *(const float4*)&Bs[kk][tn];
            const float av[4] = {a.x, a.y, a.z, a.w};
            const float bv4[4] = {b.x, b.y, b.z, b.w};
#pragma unroll
            for (int i = 0; i < 4; ++i)
#pragma unroll
                for (int j = 0; j < 4; ++j) acc[i][j] += av[i] * bv4[j];
        }
        __syncthreads();
    }

#pragma unroll
    for (int i = 0; i < 4; ++i) {
        const int r = m0 + tm + i;
#pragma unroll
        for (int j = 0; j < 4; ++j) {
            const int c = n0 + tn + j;
            out[(size_t)r * 512 + c] = acc[i][j] + bo[c];
        }
    }
}

extern "C" void kernel_launch(void* const* d_in, const int* in_sizes, int n_in,
                              void* d_out, int out_size, void* d_ws, size_t ws_size,
                              hipStream_t stream) {
    (void)in_sizes; (void)n_in; (void)out_size; (void)ws_size;

    const float* xq  = (const float*)d_in[0];
    const float* xk  = (const float*)d_in[1];
    const float* xv  = (const float*)d_in[2];
    const float* box = (const float*)d_in[3];
    const float* Wq  = (const float*)d_in[4];
    const float* bq  = (const float*)d_in[5];
    const float* Wk  = (const float*)d_in[6];
    const float* bk  = (const float*)d_in[7];
    const float* Wv  = (const float*)d_in[8];
    const float* bv  = (const float*)d_in[9];
    const float* Wo  = (const float*)d_in[10];
    const float* bo  = (const float*)d_in[11];
    const float* WGw = (const float*)d_in[12];
    const float* WGb = (const float*)d_in[13];

    // workspace: qb,kb,vt (bf16, 4MB each) | wgc (bf16, 32MB) | ao (f32, 8MB) = 52MB
    unsigned short* qb = (unsigned short*)d_ws;
    unsigned short* kb = qb + (1u << 21);
    unsigned short* vt = kb + (1u << 21);
    unsigned short* wgc = vt + (1u << 21);
    float* ao = (float*)((char*)d_ws + (44u << 20));

    k_proj<<<dim3(64, 8, 3), 256, 0, stream>>>(xq, xk, xv, Wq, Wk, Wv, bq, bk, bv, qb, kb, vt);
    k_wgc<<<dim3(512, 8), 256, 0, stream>>>(box, WGw, WGb, wgc);
    k_attn<<<dim3(512), 256, 0, stream>>>(qb, kb, vt, wgc, ao);
    k_oproj<<<dim3(64, 8), 256, 0, stream>>>(ao, Wo, bo, (float*)d_out);
}

// Round 4
// 141.848 us; speedup vs baseline: 4.9586x; 1.6002x over previous
//
#include <hip/hip_runtime.h>
#include <hip/hip_bf16.h>

#define B_ 8
#define N_ 512
#define D_ 512
#define H_ 8
#define DK_ 64

// 1000^(-f/8), f=0..7 (double-evaluated, f32-rounded)
__device__ constexpr float DMc[8] = {
    1.0f, 0.42169650342905464f, 0.1778279410038923f, 0.07498942093324559f,
    0.03162277660168379f, 0.013335214321633241f, 0.005623413251903491f,
    0.0023713737056616554f};

__device__ inline float bf2f(unsigned short u) {
    unsigned int x = ((unsigned int)u) << 16;
    return __uint_as_float(x);
}

typedef __attribute__((ext_vector_type(8))) short bf8v;
typedef __attribute__((ext_vector_type(4))) float f4v;

union AFrag { bf8v v; unsigned int u[4]; uint2 d[2]; };

__device__ inline unsigned int cvt_pk_bf16(float a, float b) {
    unsigned int r;
    asm("v_cvt_pk_bf16_f32 %0, %1, %2" : "=v"(r) : "v"(a), "v"(b));
    return r;  // bits[15:0]=bf16(a), bits[31:16]=bf16(b)
}

// x = hi + lo (both bf16), fp32-accurate reconstruction for split-MFMA
__device__ inline void split_pair(float a, float b, unsigned int& uhi, unsigned int& ulo) {
    const unsigned int uh = cvt_pk_bf16(a, b);
    const float ah = __uint_as_float(uh << 16);
    const float bh = __uint_as_float(uh & 0xFFFF0000u);
    ulo = cvt_pk_bf16(a - ah, b - bh);
    uhi = uh;
}

// ---------------------------------------------------------------------------
// K0: pre-split weights into frag-major hi/lo bf16 planes.
// Plane layout (elements): [ntile(32)][ks(16)][g(4)][hl(2)][row16][8]
//   frag elem j<4 -> k = ks*32 + 4g+j ; j>=4 -> k = ks*32 + 16 + 4g + (j-4)
// z selects Wq/Wk/Wv/Wo; each plane is 512*512*2 shorts (1 MiB).
// ---------------------------------------------------------------------------
__global__ __launch_bounds__(256) void k_split_w(
    const float* __restrict__ Wq, const float* __restrict__ Wk,
    const float* __restrict__ Wv, const float* __restrict__ Wo,
    unsigned short* __restrict__ whl)
{
    const int z = blockIdx.y;
    const float* W = (z == 0) ? Wq : (z == 1) ? Wk : (z == 2) ? Wv : Wo;
    unsigned short* out = whl + (size_t)z * 524288;

    const int nt = blockIdx.x;        // ntile 0..31
    const int t = threadIdx.x;
    const int row = t >> 4;           // 0..15 (col within ntile)
    const int ks = t & 15;

    const float* wsrc = W + (size_t)(nt * 16 + row) * 512 + ks * 32;
    float e[32];
#pragma unroll
    for (int i = 0; i < 8; ++i) {
        const float4 v4 = *(const float4*)(wsrc + 4 * i);
        e[4 * i] = v4.x; e[4 * i + 1] = v4.y; e[4 * i + 2] = v4.z; e[4 * i + 3] = v4.w;
    }
#pragma unroll
    for (int g = 0; g < 4; ++g) {
        unsigned int h0, l0, h1, l1, h2, l2, h3, l3;
        split_pair(e[4 * g + 0], e[4 * g + 1], h0, l0);
        split_pair(e[4 * g + 2], e[4 * g + 3], h1, l1);
        split_pair(e[16 + 4 * g + 0], e[16 + 4 * g + 1], h2, l2);
        split_pair(e[16 + 4 * g + 2], e[16 + 4 * g + 3], h3, l3);
        const size_t base = ((size_t)(nt * 16 + ks) * 8 + g * 2) * 128 + row * 8;
        *(uint4*)(out + base) = make_uint4(h0, h1, h2, h3);
        *(uint4*)(out + base + 128) = make_uint4(l0, l1, l2, l3);
    }
}

// ---------------------------------------------------------------------------
// Split-MFMA GEMM core: C(64x128 tile) = X(M,512) @ W^T, X fp32 converted to
// hi/lo frag-major LDS per BK=64 step; B frags direct from pre-split global.
// 4 waves (2x2), wave tile 32x64; 48 MFMAs per wave per k-step.
// ---------------------------------------------------------------------------
#define GEMM_BODY(X_PTR, WP_PTR)                                                          \
    const int m0 = blockIdx.x * 64;                                                       \
    const int n0 = blockIdx.y * 128;                                                      \
    __shared__ __align__(16) short Al[8192]; /* [ksub2][mt4][g4][hl2][row16][8] 16KB */   \
    const int t = threadIdx.x;                                                            \
    const int lane = t & 63;                                                              \
    const int wv = t >> 6;                                                                \
    const int cl = lane & 15, g = lane >> 4;                                              \
    const int wr = wv >> 1, wc = wv & 1;                                                  \
    const int srow = t >> 2;                                                              \
    const int skq = t & 3;                                                                \
    const float* xp = (X_PTR) + (size_t)(m0 + srow) * 512 + skq * 16;                     \
    short* alw = Al + ((skq >> 1) * 4096 + (srow >> 4) * 1024 + (srow & 15) * 8 +         \
                       (skq & 1) * 4);                                                    \
    f4v acc[2][4];                                                                        \
    _Pragma("unroll") for (int i = 0; i < 2; ++i)                                         \
        _Pragma("unroll") for (int j = 0; j < 4; ++j) acc[i][j] = (f4v){0.f,0.f,0.f,0.f}; \
    const int ntb = (n0 >> 4) + wc * 4;                                                   \
    for (int k0 = 0; k0 < 512; k0 += 64) {                                                \
        float4 xl[4];                                                                     \
        _Pragma("unroll") for (int i = 0; i < 4; ++i)                                     \
            xl[i] = *(const float4*)(xp + k0 + 4 * i);                                    \
        AFrag bh0[4], bl0[4];                                                             \
        _Pragma("unroll") for (int nt = 0; nt < 4; ++nt) {                                \
            const size_t be = ((size_t)((ntb + nt) * 16 + (k0 >> 5)) * 8 + g * 2) * 128   \
                              + cl * 8;                                                   \
            bh0[nt].v = *(const bf8v*)((WP_PTR) + be);                                    \
            bl0[nt].v = *(const bf8v*)((WP_PTR) + be + 128);                              \
        }                                                                                 \
        __syncthreads();                                                                  \
        {                                                                                 \
            float xe[16];                                                                 \
            _Pragma("unroll") for (int i = 0; i < 4; ++i) {                               \
                xe[4 * i] = xl[i].x; xe[4 * i + 1] = xl[i].y;                             \
                xe[4 * i + 2] = xl[i].z; xe[4 * i + 3] = xl[i].w;                         \
            }                                                                             \
            _Pragma("unroll") for (int g2 = 0; g2 < 4; ++g2) {                            \
                unsigned int h0, l0, h1, l1;                                              \
                split_pair(xe[4 * g2 + 0], xe[4 * g2 + 1], h0, l0);                       \
                split_pair(xe[4 * g2 + 2], xe[4 * g2 + 3], h1, l1);                       \
                *(uint2*)(alw + g2 * 256) = make_uint2(h0, h1);                           \
                *(uint2*)(alw + g2 * 256 + 128) = make_uint2(l0, l1);                     \
            }                                                                             \
        }                                                                                 \
        __syncthreads();                                                                  \
        AFrag bh1[4], bl1[4];                                                             \
        _Pragma("unroll") for (int nt = 0; nt < 4; ++nt) {                                \
            const size_t be = ((size_t)((ntb + nt) * 16 + (k0 >> 5) + 1) * 8 + g * 2)     \
                              * 128 + cl * 8;                                             \
            bh1[nt].v = *(const bf8v*)((WP_PTR) + be);                                    \
            bl1[nt].v = *(const bf8v*)((WP_PTR) + be + 128);                              \
        }                                                                                 \
        _Pragma("unroll") for (int ks = 0; ks < 2; ++ks) {                                \
            AFrag ah[2], alo[2];                                                          \
            _Pragma("unroll") for (int mt = 0; mt < 2; ++mt) {                            \
                const int off = ks * 8192 + (wr * 2 + mt) * 2048 + g * 512 + cl * 16;     \
                ah[mt].v = *(const bf8v*)((const char*)Al + off);                         \
                alo[mt].v = *(const bf8v*)((const char*)Al + off + 256);                  \
            }                                                                             \
            _Pragma("unroll") for (int nt = 0; nt < 4; ++nt) {                            \
                const AFrag& bhf = ks ? bh1[nt] : bh0[nt];                                \
                const AFrag& blf = ks ? bl1[nt] : bl0[nt];                                \
                _Pragma("unroll") for (int mt = 0; mt < 2; ++mt) {                        \
                    acc[mt][nt] = __builtin_amdgcn_mfma_f32_16x16x32_bf16(                \
                        ah[mt].v, bhf.v, acc[mt][nt], 0, 0, 0);                           \
                    acc[mt][nt] = __builtin_amdgcn_mfma_f32_16x16x32_bf16(                \
                        alo[mt].v, bhf.v, acc[mt][nt], 0, 0, 0);                          \
                    acc[mt][nt] = __builtin_amdgcn_mfma_f32_16x16x32_bf16(                \
                        ah[mt].v, blf.v, acc[mt][nt], 0, 0, 0);                           \
                }                                                                         \
            }                                                                             \
        }                                                                                 \
    }                                                                                     \
    const int mbase = m0 + wr * 32;                                                       \
    const int nb = n0 + wc * 64;

// ---------------------------------------------------------------------------
// K1: fused Q/K/V projection (split-MFMA). z: 0=q (bf16 BHND, x0.125),
// 1=k (bf16 BHND), 2=v transposed (bf16 BHDN).
// ---------------------------------------------------------------------------
__global__ __launch_bounds__(256, 2) void k_gemm_qkv(
    const float* __restrict__ Xq, const float* __restrict__ Xk, const float* __restrict__ Xv,
    const unsigned short* __restrict__ whl,
    const float* __restrict__ bq, const float* __restrict__ bk, const float* __restrict__ bv,
    unsigned short* __restrict__ oq, unsigned short* __restrict__ ok,
    unsigned short* __restrict__ ov)
{
    const int z = blockIdx.z;
    const float* X = (z == 0) ? Xq : (z == 1) ? Xk : Xv;
    const unsigned short* wp = whl + (size_t)z * 524288;
    const float* bias = (z == 0) ? bq : (z == 1) ? bk : bv;

    GEMM_BODY(X, wp)

    if (z == 2) {
#pragma unroll
        for (int mt = 0; mt < 2; ++mt) {
#pragma unroll
            for (int nt = 0; nt < 4; ++nt) {
                const int m = mbase + mt * 16 + 4 * g;
                const int n = nb + nt * 16 + cl;
                const float bb = bias[n];
                uint2 pk;
                pk.x = cvt_pk_bf16(acc[mt][nt][0] + bb, acc[mt][nt][1] + bb);
                pk.y = cvt_pk_bf16(acc[mt][nt][2] + bb, acc[mt][nt][3] + bb);
                *(uint2*)&ov[(((size_t)(m >> 9) * 8 + (n >> 6)) * 64 + (n & 63)) * 512 +
                             (m & 511)] = pk;
            }
        }
    } else {
        unsigned short* outp = (z == 0) ? oq : ok;
        const float sc = (z == 0) ? 0.125f : 1.0f;
#pragma unroll
        for (int mt = 0; mt < 2; ++mt) {
#pragma unroll
            for (int nt = 0; nt < 4; ++nt) {
                const int n = nb + nt * 16 + cl;
                const float bb = bias[n];
#pragma unroll
                for (int r = 0; r < 4; ++r) {
                    const int m = mbase + mt * 16 + 4 * g + r;
                    outp[(((size_t)(m >> 9) * 8 + (n >> 6)) * 512 + (m & 511)) * 64 +
                         (n & 63)] =
                        (unsigned short)cvt_pk_bf16((acc[mt][nt][r] + bb) * sc, 0.f);
                }
            }
        }
    }
}

// ---------------------------------------------------------------------------
// K4: output projection (split-MFMA). d_out(4096x512) = AO @ Wo^T + bo, f32.
// ---------------------------------------------------------------------------
__global__ __launch_bounds__(256, 2) void k_gemm_o(
    const float* __restrict__ AO, const unsigned short* __restrict__ whl,
    const float* __restrict__ bias, float* __restrict__ outp)
{
    const unsigned short* wp = whl + (size_t)3 * 524288;

    GEMM_BODY(AO, wp)

#pragma unroll
    for (int mt = 0; mt < 2; ++mt) {
#pragma unroll
        for (int nt = 0; nt < 4; ++nt) {
            const int n = nb + nt * 16 + cl;
            const float bb = bias[n];
#pragma unroll
            for (int r = 0; r < 4; ++r) {
                const int m = mbase + mt * 16 + 4 * g + r;
                outp[(size_t)m * 512 + n] = acc[mt][nt][r] + bb;
            }
        }
    }
}

// ---------------------------------------------------------------------------
// K2: pairwise box gate via MFMA (unchanged from round 2).
// ---------------------------------------------------------------------------
__global__ __launch_bounds__(256) void k_wgc(
    const float* __restrict__ box, const float* __restrict__ WGw,
    const float* __restrict__ WGb, unsigned short* __restrict__ wgc)
{
    const int n = blockIdx.x;
    const int b = blockIdx.y;

    __shared__ float S[4][520];

    const int t = threadIdx.x;

    for (int mi = t; mi < 512; mi += 256) {
        const float4 bx = *(const float4*)&box[(size_t)(b * N_ + mi) * 4];
        S[0][mi] = (bx.x + bx.z) * 0.5f;
        S[1][mi] = (bx.y + bx.w) * 0.5f;
        S[2][mi] = __logf(bx.z - bx.x + 1.0f);
        S[3][mi] = __logf(bx.w - bx.y + 1.0f);
    }

    const float4 bn = *(const float4*)&box[(size_t)(b * N_ + n) * 4];
    const float wn = bn.z - bn.x + 1.0f;
    const float hn = bn.w - bn.y + 1.0f;
    const float rwn = 1.0f / wn;
    const float rhn = 1.0f / hn;
    const float cxn = (bn.x + bn.z) * 0.5f;
    const float cyn = (bn.y + bn.w) * 0.5f;
    const float lwn = __logf(wn);
    const float lhn = __logf(hn);

    const int lane = t & 63;
    const int col = lane & 15;
    const int grp = lane >> 4;
    const int w = t >> 6;

    AFrag bs, bc;
    if (col < 8) {
        const float* wr = WGw + col * 64 + grp * 8;
#pragma unroll
        for (int j = 0; j < 4; ++j) {
            bs.u[j] = cvt_pk_bf16(wr[2 * j], wr[2 * j + 1]);
            bc.u[j] = cvt_pk_bf16(wr[32 + 2 * j], wr[32 + 2 * j + 1]);
        }
    } else {
#pragma unroll
        for (int j = 0; j < 4; ++j) { bs.u[j] = 0u; bc.u[j] = 0u; }
    }
    const float bias = (col < 8) ? WGb[col] : 0.0f;

    const float dn = (grp == 0) ? cxn : (grp == 1) ? cyn : (grp == 2) ? lwn : lhn;
    const float rA = (grp == 0) ? rwn : rhn;

    unsigned short* outb = (col < 8)
        ? wgc + ((size_t)(b * H_ + col) * N_ + n) * N_ : wgc;

    __syncthreads();

    for (int mt = 0; mt < 8; ++mt) {
        const int m0 = mt * 64 + w * 16;

        const float sv = S[grp][m0 + col];
        const float diff = dn - sv;
        const float posA = __logf(fmaxf(fabsf(diff) * rA, 1e-3f));
        const float pos = (grp < 2) ? posA : diff;
        const float p100 = 100.0f * pos;

        float sn[8], cs[8];
#pragma unroll
        for (int j = 0; j < 8; ++j) {
            const float ang = p100 * DMc[j];
            sn[j] = __sinf(ang);
            cs[j] = __cosf(ang);
        }
        AFrag as_, ac_;
#pragma unroll
        for (int j = 0; j < 4; ++j) {
            as_.u[j] = cvt_pk_bf16(sn[2 * j], sn[2 * j + 1]);
            ac_.u[j] = cvt_pk_bf16(cs[2 * j], cs[2 * j + 1]);
        }

        f4v acc = __builtin_amdgcn_mfma_f32_16x16x32_bf16(
            as_.v, bs.v, (f4v){0.f, 0.f, 0.f, 0.f}, 0, 0, 0);
        acc = __builtin_amdgcn_mfma_f32_16x16x32_bf16(ac_.v, bc.v, acc, 0, 0, 0);

        if (col < 8) {
            const int mrow = m0 + grp * 4;
            const float v0 = fmaxf(acc[0] + bias, 1e-6f);
            const float v1 = fmaxf(acc[1] + bias, 1e-6f);
            const float v2 = fmaxf(acc[2] + bias, 1e-6f);
            const float v3 = fmaxf(acc[3] + bias, 1e-6f);
            uint2 pk;
            pk.x = cvt_pk_bf16(v0, v1);
            pk.y = cvt_pk_bf16(v2, v3);
            *(uint2*)&outb[mrow] = pk;
        }
    }
}

// ---------------------------------------------------------------------------
// K3: MFMA attention, no LDS (unchanged from round 3).
// ---------------------------------------------------------------------------
__global__ __launch_bounds__(256, 2) void k_attn(
    const unsigned short* __restrict__ qb_g, const unsigned short* __restrict__ kb_g,
    const unsigned short* __restrict__ vt_g, const unsigned short* __restrict__ wgc,
    float* __restrict__ ao)
{
    const int bid = blockIdx.x;
    const int lid = ((bid & 7) << 6) | (bid >> 3);
    const int qt = lid & 7;
    const int h = (lid >> 3) & 7;
    const int b = lid >> 6;
    const int bh = b * H_ + h;

    const int t = threadIdx.x;
    const int lane = t & 63;
    const int w = t >> 6;
    const int cl = lane & 15;
    const int g = lane >> 4;

    const int q_row = qt * 64 + w * 16 + cl;

    AFrag qf[2];
    {
        const unsigned short* qrow = qb_g + ((size_t)bh * N_ + q_row) * DK_;
#pragma unroll
        for (int dkt = 0; dkt < 2; ++dkt) {
            qf[dkt].d[0] = *(const uint2*)&qrow[dkt * 32 + 4 * g];
            qf[dkt].d[1] = *(const uint2*)&qrow[dkt * 32 + 16 + 4 * g];
        }
    }

    f4v sv[32];
    const unsigned short* kbase = kb_g + (size_t)bh * N_ * DK_;
#pragma unroll
    for (int mt = 0; mt < 32; ++mt) {
        const unsigned short* krow = kbase + (size_t)(mt * 16 + cl) * DK_;
        AFrag a0, a1;
        a0.d[0] = *(const uint2*)&krow[4 * g];
        a0.d[1] = *(const uint2*)&krow[16 + 4 * g];
        a1.d[0] = *(const uint2*)&krow[32 + 4 * g];
        a1.d[1] = *(const uint2*)&krow[48 + 4 * g];
        f4v acc = __builtin_amdgcn_mfma_f32_16x16x32_bf16(
            a0.v, qf[0].v, (f4v){0.f, 0.f, 0.f, 0.f}, 0, 0, 0);
        sv[mt] = __builtin_amdgcn_mfma_f32_16x16x32_bf16(a1.v, qf[1].v, acc, 0, 0, 0);
    }

    const unsigned short* wrow = wgc + ((size_t)bh * N_ + q_row) * N_;
    float rsum = 0.f;
    AFrag pa[16];
#pragma unroll
    for (int T = 0; T < 16; ++T) {
        float p[8];
#pragma unroll
        for (int hf = 0; hf < 2; ++hf) {
            const int mt = 2 * T + hf;
            const uint2 wg2 = *(const uint2*)&wrow[mt * 16 + 4 * g];
            const float w0 = bf2f((unsigned short)wg2.x);
            const float w1 = bf2f((unsigned short)(wg2.x >> 16));
            const float w2 = bf2f((unsigned short)wg2.y);
            const float w3 = bf2f((unsigned short)(wg2.y >> 16));
            p[hf * 4 + 0] = w0 * __expf(sv[mt][0]);
            p[hf * 4 + 1] = w1 * __expf(sv[mt][1]);
            p[hf * 4 + 2] = w2 * __expf(sv[mt][2]);
            p[hf * 4 + 3] = w3 * __expf(sv[mt][3]);
            rsum += p[hf * 4 + 0] + p[hf * 4 + 1] + p[hf * 4 + 2] + p[hf * 4 + 3];
        }
        pa[T].u[0] = cvt_pk_bf16(p[0], p[1]);
        pa[T].u[1] = cvt_pk_bf16(p[2], p[3]);
        pa[T].u[2] = cvt_pk_bf16(p[4], p[5]);
        pa[T].u[3] = cvt_pk_bf16(p[6], p[7]);
    }
    rsum += __shfl_xor(rsum, 16);
    rsum += __shfl_xor(rsum, 32);

    f4v oacc[4] = {(f4v){0.f, 0.f, 0.f, 0.f}, (f4v){0.f, 0.f, 0.f, 0.f},
                   (f4v){0.f, 0.f, 0.f, 0.f}, (f4v){0.f, 0.f, 0.f, 0.f}};
    const unsigned short* vbase = vt_g + (size_t)bh * DK_ * N_;
#pragma unroll
    for (int T = 0; T < 16; ++T) {
#pragma unroll
        for (int db = 0; db < 4; ++db) {
            const unsigned short* vrow = vbase + (size_t)(db * 16 + cl) * N_ + T * 32;
            AFrag vb;
            vb.d[0] = *(const uint2*)&vrow[4 * g];
            vb.d[1] = *(const uint2*)&vrow[16 + 4 * g];
            oacc[db] = __builtin_amdgcn_mfma_f32_16x16x32_bf16(pa[T].v, vb.v, oacc[db], 0, 0, 0);
        }
    }

    float rinv[4];
#pragma unroll
    for (int r = 0; r < 4; ++r) rinv[r] = 1.0f / __shfl(rsum, 4 * g + r);
    const int q0w = qt * 64 + w * 16;
#pragma unroll
    for (int db = 0; db < 4; ++db) {
#pragma unroll
        for (int r = 0; r < 4; ++r) {
            const int qq = q0w + 4 * g + r;
            ao[((size_t)(b * N_ + qq)) * D_ + h * DK_ + db * 16 + cl] = oacc[db][r] * rinv[r];
        }
    }
}

extern "C" void kernel_launch(void* const* d_in, const int* in_sizes, int n_in,
                              void* d_out, int out_size, void* d_ws, size_t ws_size,
                              hipStream_t stream) {
    (void)in_sizes; (void)n_in; (void)out_size; (void)ws_size;

    const float* xq  = (const float*)d_in[0];
    const float* xk  = (const float*)d_in[1];
    const float* xv  = (const float*)d_in[2];
    const float* box = (const float*)d_in[3];
    const float* Wq  = (const float*)d_in[4];
    const float* bq  = (const float*)d_in[5];
    const float* Wk  = (const float*)d_in[6];
    const float* bk  = (const float*)d_in[7];
    const float* Wv  = (const float*)d_in[8];
    const float* bv  = (const float*)d_in[9];
    const float* Wo  = (const float*)d_in[10];
    const float* bo  = (const float*)d_in[11];
    const float* WGw = (const float*)d_in[12];
    const float* WGb = (const float*)d_in[13];

    // ws: qb 4M | kb 4M | vt 4M | wgc 32M | ao 8M (f32) | whl 4M  = 56 MiB
    unsigned short* qb  = (unsigned short*)d_ws;
    unsigned short* kb  = qb + (1u << 21);
    unsigned short* vt  = kb + (1u << 21);
    unsigned short* wgc = vt + (1u << 21);
    float* ao = (float*)((char*)d_ws + (44u << 20));
    unsigned short* whl = (unsigned short*)((char*)d_ws + (52u << 20));

    k_split_w<<<dim3(32, 4), 256, 0, stream>>>(Wq, Wk, Wv, Wo, whl);
    k_wgc<<<dim3(512, 8), 256, 0, stream>>>(box, WGw, WGb, wgc);
    k_gemm_qkv<<<dim3(64, 4, 3), 256, 0, stream>>>(xq, xk, xv, whl, bq, bk, bv, qb, kb, vt);
    k_attn<<<dim3(512), 256, 0, stream>>>(qb, kb, vt, wgc, ao);
    k_gemm_o<<<dim3(64, 4), 256, 0, stream>>>(ao, whl, bo, (float*)d_out);
}